// Round 1
// baseline (1779.984 us; speedup 1.0000x reference)
//
#include <hip/hip_runtime.h>

#define NODE_D 128
#define SCAN_T 256
#define SCAN_I 8   // items per thread -> 2048 per block

// ---------- weight transpose: WT[k*OUT+o] = W[o*IN+k] ----------
__global__ __launch_bounds__(256) void k_transpose(const float* __restrict__ W,
                                                   float* __restrict__ WT,
                                                   int OUT, int IN) {
    int i = blockIdx.x * 256 + threadIdx.x;
    if (i < OUT * IN) {
        int o = i / IN;
        int k = i - o * IN;
        WT[k * OUT + o] = W[i];
    }
}

// ---------- degree histogram ----------
__global__ __launch_bounds__(256) void k_hist(const int* __restrict__ dst,
                                              int* __restrict__ deg, int E) {
    int i = blockIdx.x * 256 + threadIdx.x;
    if (i < E) atomicAdd(&deg[dst[i]], 1);
}

// ---------- scan pass A: per-block sums ----------
__global__ __launch_bounds__(SCAN_T) void k_scan_bsum(const int* __restrict__ deg,
                                                      int* __restrict__ bsums, int n) {
    __shared__ int red[SCAN_T];
    int base = blockIdx.x * SCAN_T * SCAN_I + threadIdx.x * SCAN_I;
    int s = 0;
    #pragma unroll
    for (int i = 0; i < SCAN_I; ++i) {
        int idx = base + i;
        if (idx < n) s += deg[idx];
    }
    red[threadIdx.x] = s;
    __syncthreads();
    for (int st = SCAN_T / 2; st > 0; st >>= 1) {
        if (threadIdx.x < st) red[threadIdx.x] += red[threadIdx.x + st];
        __syncthreads();
    }
    if (threadIdx.x == 0) bsums[blockIdx.x] = red[0];
}

// ---------- scan pass B: exclusive scan of block sums (tiny, serial) ----------
__global__ void k_scan_bsum_excl(int* __restrict__ bsums, int nb,
                                 int* __restrict__ rowptr_last) {
    if (blockIdx.x == 0 && threadIdx.x == 0) {
        int run = 0;
        for (int i = 0; i < nb; ++i) {
            int v = bsums[i];
            bsums[i] = run;
            run += v;
        }
        rowptr_last[0] = run;  // rowptr[N] = E
    }
}

// ---------- scan pass C: final exclusive scan -> rowptr & cursor ----------
__global__ __launch_bounds__(SCAN_T) void k_scan_final(const int* __restrict__ deg,
                                                       const int* __restrict__ bsums,
                                                       int* __restrict__ rowptr,
                                                       int* __restrict__ cursor, int n) {
    __shared__ int ts[SCAN_T];
    int base = blockIdx.x * SCAN_T * SCAN_I + threadIdx.x * SCAN_I;
    int v[SCAN_I];
    int s = 0;
    #pragma unroll
    for (int i = 0; i < SCAN_I; ++i) {
        int idx = base + i;
        v[i] = (idx < n) ? deg[idx] : 0;
        s += v[i];
    }
    ts[threadIdx.x] = s;
    __syncthreads();
    // Hillis-Steele inclusive scan of thread sums
    for (int st = 1; st < SCAN_T; st <<= 1) {
        int add = (threadIdx.x >= st) ? ts[threadIdx.x - st] : 0;
        __syncthreads();
        ts[threadIdx.x] += add;
        __syncthreads();
    }
    int excl = (threadIdx.x == 0 ? 0 : ts[threadIdx.x - 1]) + bsums[blockIdx.x];
    #pragma unroll
    for (int i = 0; i < SCAN_I; ++i) {
        int idx = base + i;
        if (idx < n) { rowptr[idx] = excl; cursor[idx] = excl; }
        excl += v[i];
    }
}

// ---------- CSR fill ----------
__global__ __launch_bounds__(256) void k_fill(const int* __restrict__ src,
                                              const int* __restrict__ dst,
                                              int* __restrict__ cursor,
                                              int* __restrict__ col, int E) {
    int i = blockIdx.x * 256 + threadIdx.x;
    if (i < E) {
        int pos = atomicAdd(&cursor[dst[i]], 1);
        col[pos] = src[i];
    }
}

// ---------- mean aggregation: one block (128 thr) per node ----------
__global__ __launch_bounds__(NODE_D) void k_agg_mean(const float* __restrict__ h,
                                                     const int* __restrict__ rowptr,
                                                     const int* __restrict__ col,
                                                     float* __restrict__ mean) {
    int n = blockIdx.x;
    int d = threadIdx.x;
    int beg = rowptr[n];
    int end = rowptr[n + 1];
    float acc = 0.f;
    int j = beg;
    for (; j + 1 < end; j += 2) {
        int s0 = col[j];
        int s1 = col[j + 1];
        acc += h[(size_t)s0 * NODE_D + d];
        acc += h[(size_t)s1 * NODE_D + d];
    }
    if (j < end) acc += h[(size_t)col[j] * NODE_D + d];
    float c = (float)(end - beg);
    mean[(size_t)n * NODE_D + d] = acc / fmaxf(c, 1.f);
}

// ---------- fused row transform: out[r] = A[r]@WaT (+ B[r]@WbT) + bias (+relu) ----------
// one block (128 thr) per row; K fixed at 128; OD in {64,128}; safe in-place on B/out.
__global__ __launch_bounds__(NODE_D) void k_sage_linear(const float* __restrict__ A,
                                                        const float* __restrict__ B,
                                                        const float* __restrict__ WaT,
                                                        const float* __restrict__ WbT,
                                                        const float* __restrict__ bias,
                                                        float* __restrict__ out,
                                                        int OD, int relu) {
    __shared__ float sA[NODE_D];
    __shared__ float sB[NODE_D];
    int r = blockIdx.x;
    int t = threadIdx.x;
    sA[t] = A[(size_t)r * NODE_D + t];
    if (B) sB[t] = B[(size_t)r * NODE_D + t];
    __syncthreads();
    if (t < OD) {
        float acc = bias[t];
        if (B) {
            const float* wa = WaT + t;
            const float* wb = WbT + t;
            #pragma unroll 8
            for (int k = 0; k < NODE_D; ++k) {
                acc += sA[k] * wa[k * OD];
                acc += sB[k] * wb[k * OD];
            }
        } else {
            const float* wa = WaT + t;
            #pragma unroll 8
            for (int k = 0; k < NODE_D; ++k) {
                acc += sA[k] * wa[k * OD];
            }
        }
        if (relu) acc = fmaxf(acc, 0.f);
        out[(size_t)r * OD + t] = acc;
    }
}

extern "C" void kernel_launch(void* const* d_in, const int* in_sizes, int n_in,
                              void* d_out, int out_size, void* d_ws, size_t ws_size,
                              hipStream_t stream) {
    const float* x     = (const float*)d_in[0];
    const int*   eidx  = (const int*)d_in[1];
    const float* emb_W = (const float*)d_in[2];
    const float* emb_b = (const float*)d_in[3];
    const float* Wl0   = (const float*)d_in[4];
    const float* bl0   = (const float*)d_in[5];
    const float* Wr0   = (const float*)d_in[6];
    const float* Wl1   = (const float*)d_in[7];
    const float* bl1   = (const float*)d_in[8];
    const float* Wr1   = (const float*)d_in[9];
    const float* Wl2   = (const float*)d_in[10];
    const float* bl2   = (const float*)d_in[11];
    const float* Wr2   = (const float*)d_in[12];

    const int N = in_sizes[0] / NODE_D;
    const int E = in_sizes[1] / 2;
    const int D_OUT = out_size / N;  // 64
    const int* src = eidx;
    const int* dst = eidx + E;

    // ---- workspace layout ----
    char* w = (char*)d_ws;
    float* h    = (float*)w; w += (size_t)N * NODE_D * sizeof(float);
    float* mean = (float*)w; w += (size_t)N * NODE_D * sizeof(float);
    float* embT = (float*)w; w += (size_t)NODE_D * NODE_D * sizeof(float);
    float* Wl0T = (float*)w; w += (size_t)NODE_D * NODE_D * sizeof(float);
    float* Wr0T = (float*)w; w += (size_t)NODE_D * NODE_D * sizeof(float);
    float* Wl1T = (float*)w; w += (size_t)NODE_D * NODE_D * sizeof(float);
    float* Wr1T = (float*)w; w += (size_t)NODE_D * NODE_D * sizeof(float);
    float* Wl2T = (float*)w; w += (size_t)NODE_D * D_OUT * sizeof(float);
    float* Wr2T = (float*)w; w += (size_t)NODE_D * D_OUT * sizeof(float);
    int* deg    = (int*)w;  w += (size_t)N * sizeof(int);
    int* rowptr = (int*)w;  w += (size_t)(N + 1) * sizeof(int);
    int* cursor = (int*)w;  w += (size_t)N * sizeof(int);
    int* bsums  = (int*)w;  w += (size_t)256 * sizeof(int);
    int* col    = (int*)w;  w += (size_t)E * sizeof(int);

    const int TPB = 256;
    const int wgrid = (NODE_D * NODE_D + TPB - 1) / TPB;  // 64 blocks
    const int wgrid2 = (NODE_D * D_OUT + TPB - 1) / TPB;  // 32 blocks

    // ---- transpose all weights once ----
    hipLaunchKernelGGL(k_transpose, dim3(wgrid), dim3(TPB), 0, stream, emb_W, embT, NODE_D, NODE_D);
    hipLaunchKernelGGL(k_transpose, dim3(wgrid), dim3(TPB), 0, stream, Wl0, Wl0T, NODE_D, NODE_D);
    hipLaunchKernelGGL(k_transpose, dim3(wgrid), dim3(TPB), 0, stream, Wr0, Wr0T, NODE_D, NODE_D);
    hipLaunchKernelGGL(k_transpose, dim3(wgrid), dim3(TPB), 0, stream, Wl1, Wl1T, NODE_D, NODE_D);
    hipLaunchKernelGGL(k_transpose, dim3(wgrid), dim3(TPB), 0, stream, Wr1, Wr1T, NODE_D, NODE_D);
    hipLaunchKernelGGL(k_transpose, dim3(wgrid2), dim3(TPB), 0, stream, Wl2, Wl2T, D_OUT, NODE_D);
    hipLaunchKernelGGL(k_transpose, dim3(wgrid2), dim3(TPB), 0, stream, Wr2, Wr2T, D_OUT, NODE_D);

    // ---- CSR build (deg -> rowptr -> col) ----
    hipMemsetAsync(deg, 0, (size_t)N * sizeof(int), stream);
    hipLaunchKernelGGL(k_hist, dim3((E + TPB - 1) / TPB), dim3(TPB), 0, stream, dst, deg, E);
    const int NB = (N + SCAN_T * SCAN_I - 1) / (SCAN_T * SCAN_I);
    hipLaunchKernelGGL(k_scan_bsum, dim3(NB), dim3(SCAN_T), 0, stream, deg, bsums, N);
    hipLaunchKernelGGL(k_scan_bsum_excl, dim3(1), dim3(1), 0, stream, bsums, NB, rowptr + N);
    hipLaunchKernelGGL(k_scan_final, dim3(NB), dim3(SCAN_T), 0, stream, deg, bsums, rowptr, cursor, N);
    hipLaunchKernelGGL(k_fill, dim3((E + TPB - 1) / TPB), dim3(TPB), 0, stream, src, dst, cursor, col, E);

    // ---- embedding: h = x @ emb_W.T + emb_b ----
    hipLaunchKernelGGL(k_sage_linear, dim3(N), dim3(NODE_D), 0, stream,
                       x, (const float*)nullptr, embT, (const float*)nullptr, emb_b, h, NODE_D, 0);

    // ---- layer 0: h = relu(mean@Wl0.T + bl0 + h@Wr0.T) ----
    hipLaunchKernelGGL(k_agg_mean, dim3(N), dim3(NODE_D), 0, stream, h, rowptr, col, mean);
    hipLaunchKernelGGL(k_sage_linear, dim3(N), dim3(NODE_D), 0, stream,
                       mean, h, Wl0T, Wr0T, bl0, h, NODE_D, 1);

    // ---- layer 1 ----
    hipLaunchKernelGGL(k_agg_mean, dim3(N), dim3(NODE_D), 0, stream, h, rowptr, col, mean);
    hipLaunchKernelGGL(k_sage_linear, dim3(N), dim3(NODE_D), 0, stream,
                       mean, h, Wl1T, Wr1T, bl1, h, NODE_D, 1);

    // ---- layer 2 (no relu, OD=64, write d_out) ----
    hipLaunchKernelGGL(k_agg_mean, dim3(N), dim3(NODE_D), 0, stream, h, rowptr, col, mean);
    hipLaunchKernelGGL(k_sage_linear, dim3(N), dim3(NODE_D), 0, stream,
                       mean, h, Wl2T, Wr2T, bl2, (float*)d_out, D_OUT, 0);
}

// Round 2
// 880.306 us; speedup vs baseline: 2.0220x; 2.0220x over previous
//
#include <hip/hip_runtime.h>

#define NODE_D 128
#define SCAN_T 256
#define SCAN_I 8   // items per thread -> 2048 per block

// ---------- weight transpose: WT[k*OUT+o] = W[o*IN+k] ----------
__global__ __launch_bounds__(256) void k_transpose(const float* __restrict__ W,
                                                   float* __restrict__ WT,
                                                   int OUT, int IN) {
    int i = blockIdx.x * 256 + threadIdx.x;
    if (i < OUT * IN) {
        int o = i / IN;
        int k = i - o * IN;
        WT[k * OUT + o] = W[i];
    }
}

// ---------- degree histogram ----------
__global__ __launch_bounds__(256) void k_hist(const int* __restrict__ dst,
                                              int* __restrict__ deg, int E) {
    int i = blockIdx.x * 256 + threadIdx.x;
    if (i < E) atomicAdd(&deg[dst[i]], 1);
}

// ---------- scan pass A: per-block sums ----------
__global__ __launch_bounds__(SCAN_T) void k_scan_bsum(const int* __restrict__ deg,
                                                      int* __restrict__ bsums, int n) {
    __shared__ int red[SCAN_T];
    int base = blockIdx.x * SCAN_T * SCAN_I + threadIdx.x * SCAN_I;
    int s = 0;
    #pragma unroll
    for (int i = 0; i < SCAN_I; ++i) {
        int idx = base + i;
        if (idx < n) s += deg[idx];
    }
    red[threadIdx.x] = s;
    __syncthreads();
    for (int st = SCAN_T / 2; st > 0; st >>= 1) {
        if (threadIdx.x < st) red[threadIdx.x] += red[threadIdx.x + st];
        __syncthreads();
    }
    if (threadIdx.x == 0) bsums[blockIdx.x] = red[0];
}

// ---------- scan pass B: exclusive scan of block sums (tiny, serial) ----------
__global__ void k_scan_bsum_excl(int* __restrict__ bsums, int nb,
                                 int* __restrict__ rowptr_last) {
    if (blockIdx.x == 0 && threadIdx.x == 0) {
        int run = 0;
        for (int i = 0; i < nb; ++i) {
            int v = bsums[i];
            bsums[i] = run;
            run += v;
        }
        rowptr_last[0] = run;  // rowptr[N] = E
    }
}

// ---------- scan pass C: final exclusive scan -> rowptr & cursor ----------
__global__ __launch_bounds__(SCAN_T) void k_scan_final(const int* __restrict__ deg,
                                                       const int* __restrict__ bsums,
                                                       int* __restrict__ rowptr,
                                                       int* __restrict__ cursor, int n) {
    __shared__ int ts[SCAN_T];
    int base = blockIdx.x * SCAN_T * SCAN_I + threadIdx.x * SCAN_I;
    int v[SCAN_I];
    int s = 0;
    #pragma unroll
    for (int i = 0; i < SCAN_I; ++i) {
        int idx = base + i;
        v[i] = (idx < n) ? deg[idx] : 0;
        s += v[i];
    }
    ts[threadIdx.x] = s;
    __syncthreads();
    for (int st = 1; st < SCAN_T; st <<= 1) {
        int add = (threadIdx.x >= st) ? ts[threadIdx.x - st] : 0;
        __syncthreads();
        ts[threadIdx.x] += add;
        __syncthreads();
    }
    int excl = (threadIdx.x == 0 ? 0 : ts[threadIdx.x - 1]) + bsums[blockIdx.x];
    #pragma unroll
    for (int i = 0; i < SCAN_I; ++i) {
        int idx = base + i;
        if (idx < n) { rowptr[idx] = excl; cursor[idx] = excl; }
        excl += v[i];
    }
}

// ---------- CSR fill ----------
__global__ __launch_bounds__(256) void k_fill(const int* __restrict__ src,
                                              const int* __restrict__ dst,
                                              int* __restrict__ cursor,
                                              int* __restrict__ col, int E) {
    int i = blockIdx.x * 256 + threadIdx.x;
    if (i < E) {
        int pos = atomicAdd(&cursor[dst[i]], 1);
        col[pos] = src[i];
    }
}

// ---------- mean aggregation: one wave (64 lanes) per node ----------
template<int D>
__global__ __launch_bounds__(256) void k_agg(const float* __restrict__ h,
                                             const int* __restrict__ rowptr,
                                             const int* __restrict__ col,
                                             float* __restrict__ mean, int N) {
    int node = blockIdx.x * 4 + (threadIdx.x >> 6);
    if (node >= N) return;
    int lane = threadIdx.x & 63;
    int beg = rowptr[node];
    int end = rowptr[node + 1];
    float inv = 1.f / fmaxf((float)(end - beg), 1.f);
    if constexpr (D == 128) {
        const float* base = h + lane * 2;
        float ax = 0.f, ay = 0.f;
        int j = beg;
        for (; j + 3 < end; j += 4) {
            int s0 = col[j], s1 = col[j + 1], s2 = col[j + 2], s3 = col[j + 3];
            float2 v0 = *(const float2*)&base[(size_t)s0 * D];
            float2 v1 = *(const float2*)&base[(size_t)s1 * D];
            float2 v2 = *(const float2*)&base[(size_t)s2 * D];
            float2 v3 = *(const float2*)&base[(size_t)s3 * D];
            ax += (v0.x + v1.x) + (v2.x + v3.x);
            ay += (v0.y + v1.y) + (v2.y + v3.y);
        }
        for (; j < end; ++j) {
            float2 v = *(const float2*)&base[(size_t)col[j] * D];
            ax += v.x; ay += v.y;
        }
        float2 o; o.x = ax * inv; o.y = ay * inv;
        *(float2*)&mean[(size_t)node * D + lane * 2] = o;
    } else {
        const float* base = h + lane;
        float ax = 0.f;
        int j = beg;
        for (; j + 3 < end; j += 4) {
            int s0 = col[j], s1 = col[j + 1], s2 = col[j + 2], s3 = col[j + 3];
            ax += (base[(size_t)s0 * D] + base[(size_t)s1 * D]) +
                  (base[(size_t)s2 * D] + base[(size_t)s3 * D]);
        }
        for (; j < end; ++j) ax += base[(size_t)col[j] * D];
        mean[(size_t)node * D + lane] = ax * inv;
    }
}

// ---------- register-tiled dense: out = A@Wa (+ B@Wb) + bias (+add) (+relu) ----------
// 512 threads, tile BM=128 rows x OD cols. Weights (transposed, [K=128][OD]) staged
// fully in LDS. Per-thread micro-tile: 4 rows x (OD/16) cols, cols split in groups
// of 4 at {g*64 + tc*4} so a wave's weight ds_read_b128 spans contiguous 256B
// (no 4-way bank conflict). A-tile stored k-major with +4 pad.
template<int OD, bool HAS_B, bool HAS_ADD, bool RELU>
__global__ __launch_bounds__(512) void k_dense(const float* __restrict__ A,
                                               const float* __restrict__ B,
                                               const float* __restrict__ Wa,
                                               const float* __restrict__ Wb,
                                               const float* __restrict__ bias,
                                               const float* __restrict__ add,
                                               float* __restrict__ out, int N) {
    constexpr int BM = 128;
    constexpr int KB = 16;
    constexpr int RS = BM + 4;     // padded row length for k-major tiles
    constexpr int G  = OD / 64;    // col groups of 4 per thread (2 or 1)

    __shared__ float sWa[128 * OD];
    __shared__ float sWb[HAS_B ? 128 * OD : 1];
    __shared__ float sA[KB * RS];
    __shared__ float sB[HAS_B ? KB * RS : 1];

    const int t  = threadIdx.x;
    const int tc = t & 15;         // 16 col groups
    const int tr = t >> 4;         // 32 row groups (4 rows each)
    const int r0 = blockIdx.x * BM;

    // preload full weight matrices into LDS
    for (int i = t * 4; i < 128 * OD; i += 512 * 4) {
        *(float4*)&sWa[i] = *(const float4*)&Wa[i];
        if (HAS_B) *(float4*)&sWb[i] = *(const float4*)&Wb[i];
    }

    float bv[G][4];
    #pragma unroll
    for (int g = 0; g < G; ++g)
        #pragma unroll
        for (int j = 0; j < 4; ++j)
            bv[g][j] = bias ? bias[g * 64 + tc * 4 + j] : 0.f;

    float acc[4][G][4];
    #pragma unroll
    for (int i = 0; i < 4; ++i)
        #pragma unroll
        for (int g = 0; g < G; ++g)
            #pragma unroll
            for (int j = 0; j < 4; ++j)
                acc[i][g][j] = bv[g][j];

    // staging indices
    const int srow = t >> 2;          // 0..127
    const int kq   = (t & 3) * 4;     // 0,4,8,12
    const int grow = r0 + srow;
    const bool rok = grow < N;
    const float* pA = A + (size_t)grow * 128;
    const float* pB = HAS_B ? (B + (size_t)grow * 128) : nullptr;

    for (int kc = 0; kc < 128; kc += KB) {
        float4 va, vb;
        va.x = va.y = va.z = va.w = 0.f;
        if (rok) va = *(const float4*)&pA[kc + kq];
        if (HAS_B) {
            vb.x = vb.y = vb.z = vb.w = 0.f;
            if (rok) vb = *(const float4*)&pB[kc + kq];
        }
        __syncthreads();   // previous compute done (also orders weight preload)
        sA[(kq + 0) * RS + srow] = va.x;
        sA[(kq + 1) * RS + srow] = va.y;
        sA[(kq + 2) * RS + srow] = va.z;
        sA[(kq + 3) * RS + srow] = va.w;
        if (HAS_B) {
            sB[(kq + 0) * RS + srow] = vb.x;
            sB[(kq + 1) * RS + srow] = vb.y;
            sB[(kq + 2) * RS + srow] = vb.z;
            sB[(kq + 3) * RS + srow] = vb.w;
        }
        __syncthreads();
        #pragma unroll
        for (int k = 0; k < KB; ++k) {
            float4 a4 = *(float4*)&sA[k * RS + tr * 4];
            float a[4] = {a4.x, a4.y, a4.z, a4.w};
            float b[4];
            if (HAS_B) {
                float4 b4 = *(float4*)&sB[k * RS + tr * 4];
                b[0] = b4.x; b[1] = b4.y; b[2] = b4.z; b[3] = b4.w;
            }
            #pragma unroll
            for (int g = 0; g < G; ++g) {
                float4 wa4 = *(float4*)&sWa[(kc + k) * OD + g * 64 + tc * 4];
                float wa[4] = {wa4.x, wa4.y, wa4.z, wa4.w};
                float wb[4];
                if (HAS_B) {
                    float4 wb4 = *(float4*)&sWb[(kc + k) * OD + g * 64 + tc * 4];
                    wb[0] = wb4.x; wb[1] = wb4.y; wb[2] = wb4.z; wb[3] = wb4.w;
                }
                #pragma unroll
                for (int i = 0; i < 4; ++i)
                    #pragma unroll
                    for (int j = 0; j < 4; ++j) {
                        acc[i][g][j] += a[i] * wa[j];
                        if (HAS_B) acc[i][g][j] += b[i] * wb[j];
                    }
            }
        }
    }

    // epilogue
    #pragma unroll
    for (int i = 0; i < 4; ++i) {
        int gr = r0 + tr * 4 + i;
        if (gr < N) {
            #pragma unroll
            for (int g = 0; g < G; ++g) {
                int c = g * 64 + tc * 4;
                float4 v;
                v.x = acc[i][g][0]; v.y = acc[i][g][1];
                v.z = acc[i][g][2]; v.w = acc[i][g][3];
                if (HAS_ADD) {
                    float4 ad = *(const float4*)&add[(size_t)gr * OD + c];
                    v.x += ad.x; v.y += ad.y; v.z += ad.z; v.w += ad.w;
                }
                if (RELU) {
                    v.x = fmaxf(v.x, 0.f); v.y = fmaxf(v.y, 0.f);
                    v.z = fmaxf(v.z, 0.f); v.w = fmaxf(v.w, 0.f);
                }
                *(float4*)&out[(size_t)gr * OD + c] = v;
            }
        }
    }
}

extern "C" void kernel_launch(void* const* d_in, const int* in_sizes, int n_in,
                              void* d_out, int out_size, void* d_ws, size_t ws_size,
                              hipStream_t stream) {
    const float* x     = (const float*)d_in[0];
    const int*   eidx  = (const int*)d_in[1];
    const float* emb_W = (const float*)d_in[2];
    const float* emb_b = (const float*)d_in[3];
    const float* Wl0   = (const float*)d_in[4];
    const float* bl0   = (const float*)d_in[5];
    const float* Wr0   = (const float*)d_in[6];
    const float* Wl1   = (const float*)d_in[7];
    const float* bl1   = (const float*)d_in[8];
    const float* Wr1   = (const float*)d_in[9];
    const float* Wl2   = (const float*)d_in[10];
    const float* bl2   = (const float*)d_in[11];
    const float* Wr2   = (const float*)d_in[12];

    const int N = in_sizes[0] / NODE_D;
    const int E = in_sizes[1] / 2;
    const int D_OUT = out_size / N;  // 64
    const int* src = eidx;
    const int* dst = eidx + E;

    // ---- workspace layout ----
    char* w = (char*)d_ws;
    float* h    = (float*)w; w += (size_t)N * NODE_D * sizeof(float);
    float* mean = (float*)w; w += (size_t)N * NODE_D * sizeof(float);
    float* embT = (float*)w; w += (size_t)NODE_D * NODE_D * sizeof(float);
    float* Wl0T = (float*)w; w += (size_t)NODE_D * NODE_D * sizeof(float);
    float* Wr0T = (float*)w; w += (size_t)NODE_D * NODE_D * sizeof(float);
    float* Wl1T = (float*)w; w += (size_t)NODE_D * NODE_D * sizeof(float);
    float* Wr1T = (float*)w; w += (size_t)NODE_D * NODE_D * sizeof(float);
    float* Wl2T = (float*)w; w += (size_t)NODE_D * D_OUT * sizeof(float);
    float* Wr2T = (float*)w; w += (size_t)NODE_D * D_OUT * sizeof(float);
    int* deg    = (int*)w;  w += (size_t)N * sizeof(int);
    int* rowptr = (int*)w;  w += (size_t)(N + 1) * sizeof(int);
    int* cursor = (int*)w;  w += (size_t)N * sizeof(int);
    int* bsums  = (int*)w;  w += (size_t)256 * sizeof(int);
    int* col    = (int*)w;  w += (size_t)E * sizeof(int);

    // layer-2 pre-transformed buffers alias `mean` (N*64 each)
    float* g2 = mean;
    float* ga = mean + (size_t)N * 64;

    const int TPB = 256;
    const int wgrid  = (NODE_D * NODE_D + TPB - 1) / TPB;
    const int wgrid2 = (NODE_D * D_OUT + TPB - 1) / TPB;

    hipLaunchKernelGGL(k_transpose, dim3(wgrid), dim3(TPB), 0, stream, emb_W, embT, NODE_D, NODE_D);
    hipLaunchKernelGGL(k_transpose, dim3(wgrid), dim3(TPB), 0, stream, Wl0, Wl0T, NODE_D, NODE_D);
    hipLaunchKernelGGL(k_transpose, dim3(wgrid), dim3(TPB), 0, stream, Wr0, Wr0T, NODE_D, NODE_D);
    hipLaunchKernelGGL(k_transpose, dim3(wgrid), dim3(TPB), 0, stream, Wl1, Wl1T, NODE_D, NODE_D);
    hipLaunchKernelGGL(k_transpose, dim3(wgrid), dim3(TPB), 0, stream, Wr1, Wr1T, NODE_D, NODE_D);
    hipLaunchKernelGGL(k_transpose, dim3(wgrid2), dim3(TPB), 0, stream, Wl2, Wl2T, D_OUT, NODE_D);
    hipLaunchKernelGGL(k_transpose, dim3(wgrid2), dim3(TPB), 0, stream, Wr2, Wr2T, D_OUT, NODE_D);

    // ---- CSR build ----
    hipMemsetAsync(deg, 0, (size_t)N * sizeof(int), stream);
    hipLaunchKernelGGL(k_hist, dim3((E + TPB - 1) / TPB), dim3(TPB), 0, stream, dst, deg, E);
    const int NB = (N + SCAN_T * SCAN_I - 1) / (SCAN_T * SCAN_I);
    hipLaunchKernelGGL(k_scan_bsum, dim3(NB), dim3(SCAN_T), 0, stream, deg, bsums, N);
    hipLaunchKernelGGL(k_scan_bsum_excl, dim3(1), dim3(1), 0, stream, bsums, NB, rowptr + N);
    hipLaunchKernelGGL(k_scan_final, dim3(NB), dim3(SCAN_T), 0, stream, deg, bsums, rowptr, cursor, N);
    hipLaunchKernelGGL(k_fill, dim3((E + TPB - 1) / TPB), dim3(TPB), 0, stream, src, dst, cursor, col, E);

    const int dgrid = (N + 127) / 128;
    const int agrid = (N + 3) / 4;

    // ---- embedding: h = x @ emb_W.T + emb_b ----
    hipLaunchKernelGGL((k_dense<128, false, false, false>), dim3(dgrid), dim3(512), 0, stream,
                       x, (const float*)nullptr, embT, (const float*)nullptr, emb_b,
                       (const float*)nullptr, h, N);

    // ---- layer 0 ----
    hipLaunchKernelGGL((k_agg<128>), dim3(agrid), dim3(256), 0, stream, h, rowptr, col, mean, N);
    hipLaunchKernelGGL((k_dense<128, true, false, true>), dim3(dgrid), dim3(512), 0, stream,
                       mean, h, Wl0T, Wr0T, bl0, (const float*)nullptr, h, N);

    // ---- layer 1 ----
    hipLaunchKernelGGL((k_agg<128>), dim3(agrid), dim3(256), 0, stream, h, rowptr, col, mean, N);
    hipLaunchKernelGGL((k_dense<128, true, false, true>), dim3(dgrid), dim3(512), 0, stream,
                       mean, h, Wl1T, Wr1T, bl1, (const float*)nullptr, h, N);

    // ---- layer 2: pre-transform, aggregate in 64-dim, then root + add ----
    hipLaunchKernelGGL((k_dense<64, false, false, false>), dim3(dgrid), dim3(512), 0, stream,
                       h, (const float*)nullptr, Wl2T, (const float*)nullptr,
                       (const float*)nullptr, (const float*)nullptr, g2, N);
    hipLaunchKernelGGL((k_agg<64>), dim3(agrid), dim3(256), 0, stream, g2, rowptr, col, ga, N);
    hipLaunchKernelGGL((k_dense<64, false, true, false>), dim3(dgrid), dim3(512), 0, stream,
                       h, (const float*)nullptr, Wr2T, (const float*)nullptr, bl2,
                       ga, (float*)d_out, N);
}

// Round 3
// 516.131 us; speedup vs baseline: 3.4487x; 1.7056x over previous
//
#include <hip/hip_runtime.h>

typedef __attribute__((ext_vector_type(8))) short short8;
typedef __attribute__((ext_vector_type(4))) float f32x4;

#define NODE_D 128
#define SCAN_T 256
#define SCAN_I 8

__device__ __forceinline__ float bf2f(ushort u) {
    union { uint i; float f; } c; c.i = ((uint)u) << 16; return c.f;
}
__device__ __forceinline__ ushort f2bf(float f) {
    union { float f; uint i; } c; c.f = f;
    return (ushort)((c.i + 0x7FFF + ((c.i >> 16) & 1)) >> 16);
}

// ---------- f32 -> bf16 convert (vectorized, grid-stride over groups of 4) ----------
__global__ __launch_bounds__(256) void k_cvt(const float* __restrict__ src,
                                             ushort* __restrict__ dst, int n4) {
    int i = blockIdx.x * 256 + threadIdx.x;
    int stride = gridDim.x * 256;
    for (; i < n4; i += stride) {
        float4 v = *(const float4*)(src + (size_t)i * 4);
        ushort4 o;
        o.x = f2bf(v.x); o.y = f2bf(v.y); o.z = f2bf(v.z); o.w = f2bf(v.w);
        *(ushort4*)(dst + (size_t)i * 4) = o;
    }
}

// ---------- all 7 weight matrices f32 -> bf16, concatenated dst ----------
__global__ __launch_bounds__(256) void k_cvt_w(const float* __restrict__ s0, const float* __restrict__ s1,
                                               const float* __restrict__ s2, const float* __restrict__ s3,
                                               const float* __restrict__ s4, const float* __restrict__ s5,
                                               const float* __restrict__ s6, ushort* __restrict__ dst) {
    int i = blockIdx.x * 256 + threadIdx.x;
    if (i >= 98304) return;
    const float* s; int off;
    if (i < 16384)      { s = s0; off = i; }
    else if (i < 32768) { s = s1; off = i - 16384; }
    else if (i < 49152) { s = s2; off = i - 32768; }
    else if (i < 65536) { s = s3; off = i - 49152; }
    else if (i < 81920) { s = s4; off = i - 65536; }
    else if (i < 90112) { s = s5; off = i - 81920; }
    else                { s = s6; off = i - 90112; }
    dst[i] = f2bf(s[off]);
}

// ---------- degree histogram ----------
__global__ __launch_bounds__(256) void k_hist(const int* __restrict__ dst,
                                              int* __restrict__ deg, int E) {
    int i = blockIdx.x * 256 + threadIdx.x;
    if (i < E) atomicAdd(&deg[dst[i]], 1);
}

// ---------- scan pass A ----------
__global__ __launch_bounds__(SCAN_T) void k_scan_bsum(const int* __restrict__ deg,
                                                      int* __restrict__ bsums, int n) {
    __shared__ int red[SCAN_T];
    int base = blockIdx.x * SCAN_T * SCAN_I + threadIdx.x * SCAN_I;
    int s = 0;
    #pragma unroll
    for (int i = 0; i < SCAN_I; ++i) {
        int idx = base + i;
        if (idx < n) s += deg[idx];
    }
    red[threadIdx.x] = s;
    __syncthreads();
    for (int st = SCAN_T / 2; st > 0; st >>= 1) {
        if (threadIdx.x < st) red[threadIdx.x] += red[threadIdx.x + st];
        __syncthreads();
    }
    if (threadIdx.x == 0) bsums[blockIdx.x] = red[0];
}

// ---------- scan pass B ----------
__global__ void k_scan_bsum_excl(int* __restrict__ bsums, int nb,
                                 int* __restrict__ rowptr_last) {
    if (blockIdx.x == 0 && threadIdx.x == 0) {
        int run = 0;
        for (int i = 0; i < nb; ++i) {
            int v = bsums[i];
            bsums[i] = run;
            run += v;
        }
        rowptr_last[0] = run;
    }
}

// ---------- scan pass C ----------
__global__ __launch_bounds__(SCAN_T) void k_scan_final(const int* __restrict__ deg,
                                                       const int* __restrict__ bsums,
                                                       int* __restrict__ rowptr,
                                                       int* __restrict__ cursor, int n) {
    __shared__ int ts[SCAN_T];
    int base = blockIdx.x * SCAN_T * SCAN_I + threadIdx.x * SCAN_I;
    int v[SCAN_I];
    int s = 0;
    #pragma unroll
    for (int i = 0; i < SCAN_I; ++i) {
        int idx = base + i;
        v[i] = (idx < n) ? deg[idx] : 0;
        s += v[i];
    }
    ts[threadIdx.x] = s;
    __syncthreads();
    for (int st = 1; st < SCAN_T; st <<= 1) {
        int add = (threadIdx.x >= st) ? ts[threadIdx.x - st] : 0;
        __syncthreads();
        ts[threadIdx.x] += add;
        __syncthreads();
    }
    int excl = (threadIdx.x == 0 ? 0 : ts[threadIdx.x - 1]) + bsums[blockIdx.x];
    #pragma unroll
    for (int i = 0; i < SCAN_I; ++i) {
        int idx = base + i;
        if (idx < n) { rowptr[idx] = excl; cursor[idx] = excl; }
        excl += v[i];
    }
}

// ---------- CSR fill ----------
__global__ __launch_bounds__(256) void k_fill(const int* __restrict__ src,
                                              const int* __restrict__ dst,
                                              int* __restrict__ cursor,
                                              int* __restrict__ col, int E) {
    int i = blockIdx.x * 256 + threadIdx.x;
    if (i < E) {
        int pos = atomicAdd(&cursor[dst[i]], 1);
        col[pos] = src[i];
    }
}

// ---------- mean aggregation over bf16 activations: one wave per node ----------
template<int D>
__global__ __launch_bounds__(256) void k_aggb(const ushort* __restrict__ h,
                                              const int* __restrict__ rowptr,
                                              const int* __restrict__ col,
                                              ushort* __restrict__ mean, int N) {
    int node = blockIdx.x * 4 + (threadIdx.x >> 6);
    if (node >= N) return;
    int lane = threadIdx.x & 63;
    int beg = rowptr[node];
    int end = rowptr[node + 1];
    float inv = 1.f / fmaxf((float)(end - beg), 1.f);
    if constexpr (D == 128) {
        const ushort* base = h + lane * 2;
        float ax = 0.f, ay = 0.f;
        int j = beg;
        for (; j + 3 < end; j += 4) {
            int s0 = col[j], s1 = col[j + 1], s2 = col[j + 2], s3 = col[j + 3];
            uint v0 = *(const uint*)(base + (size_t)s0 * 128);
            uint v1 = *(const uint*)(base + (size_t)s1 * 128);
            uint v2 = *(const uint*)(base + (size_t)s2 * 128);
            uint v3 = *(const uint*)(base + (size_t)s3 * 128);
            ax += (bf2f((ushort)v0) + bf2f((ushort)v1)) + (bf2f((ushort)v2) + bf2f((ushort)v3));
            ay += (bf2f((ushort)(v0 >> 16)) + bf2f((ushort)(v1 >> 16))) +
                  (bf2f((ushort)(v2 >> 16)) + bf2f((ushort)(v3 >> 16)));
        }
        for (; j < end; ++j) {
            uint v = *(const uint*)(base + (size_t)col[j] * 128);
            ax += bf2f((ushort)v);
            ay += bf2f((ushort)(v >> 16));
        }
        uint o = (uint)f2bf(ax * inv) | ((uint)f2bf(ay * inv) << 16);
        *(uint*)(mean + (size_t)node * 128 + lane * 2) = o;
    } else {
        const ushort* base = h + lane;
        float ax = 0.f;
        int j = beg;
        for (; j + 3 < end; j += 4) {
            int s0 = col[j], s1 = col[j + 1], s2 = col[j + 2], s3 = col[j + 3];
            ax += (bf2f(base[(size_t)s0 * D]) + bf2f(base[(size_t)s1 * D])) +
                  (bf2f(base[(size_t)s2 * D]) + bf2f(base[(size_t)s3 * D]));
        }
        for (; j < end; ++j) ax += bf2f(base[(size_t)col[j] * D]);
        mean[(size_t)node * D + lane] = f2bf(ax * inv);
    }
}

// ---------- MFMA dense: out = A@W0^T (+ A1@W1^T) [+bias] [+add] [+relu] ----------
// A sources: [N][128] bf16 row-major. W sources: [OD][128] bf16 row-major (orig layout).
// Tile: 128 rows x OD cols, 256 threads = 4 waves. BK=64 chunks; K=128 (or 256 dual).
// LDS tiles stored [dim][64] bf16 with XOR swizzle byte^=((row&7)<<4) so 16-lane
// ds_read_b128 fragment loads are ~2-way instead of 16-way bank-conflicted.
// Fragment layout (16x16x32): A row = lane&15, k = (lane>>4)*8 + j (8 contiguous);
// B col = lane&15, same k. C/D: col = lane&15, row = (lane>>4)*4 + reg.
template<int OD, bool DUAL, bool HAS_ADD, bool RELU, bool OUT_F32>
__global__ __launch_bounds__(256) void k_mm(const ushort* __restrict__ A0,
                                            const ushort* __restrict__ A1,
                                            const ushort* __restrict__ W0,
                                            const ushort* __restrict__ W1,
                                            const float* __restrict__ bias,
                                            const ushort* __restrict__ add,
                                            void* __restrict__ outp, int N) {
    constexpr int NK    = DUAL ? 4 : 2;
    constexpr int M_REP = (OD == 128) ? 4 : 2;
    constexpr int N_REP = 4;
    constexpr int WROWS = M_REP * 16;

    __shared__ __align__(16) ushort sA[128 * 64];
    __shared__ __align__(16) ushort sW[OD * 64];

    const int t    = threadIdx.x;
    const int wid  = t >> 6;
    const int lane = t & 63;
    const int l15  = lane & 15;
    const int lhi  = lane >> 4;
    const int r0   = blockIdx.x * 128;

    int wm, wn0;
    if (OD == 128) { wm = wid >> 1; wn0 = (wid & 1) * 64; }
    else           { wm = wid;      wn0 = 0; }

    f32x4 zero = {0.f, 0.f, 0.f, 0.f};
    f32x4 acc[M_REP][N_REP];
    #pragma unroll
    for (int m = 0; m < M_REP; ++m)
        #pragma unroll
        for (int n = 0; n < N_REP; ++n) acc[m][n] = zero;

    for (int kc = 0; kc < NK; ++kc) {
        const ushort* As = (DUAL && kc >= 2) ? A1 : A0;
        const ushort* Ws = (DUAL && kc >= 2) ? W1 : W0;
        const int kloc = (kc & 1) * 64;

        __syncthreads();
        // stage A tile: 128 rows x 64 k (1024 x 16B slots)
        #pragma unroll
        for (int it = 0; it < 4; ++it) {
            int slot = it * 256 + t;
            int row = slot >> 3, k8 = slot & 7;
            int gr = r0 + row; if (gr >= N) gr = N - 1;
            short8 v = *(const short8*)(As + (size_t)gr * 128 + kloc + k8 * 8);
            *(short8*)((char*)sA + ((row * 128 + k8 * 16) ^ ((row & 7) << 4))) = v;
        }
        // stage W tile: OD rows x 64 k
        #pragma unroll
        for (int it = 0; it < OD / 32; ++it) {
            int slot = it * 256 + t;
            int row = slot >> 3, k8 = slot & 7;
            short8 v = *(const short8*)(Ws + (size_t)row * 128 + kloc + k8 * 8);
            *(short8*)((char*)sW + ((row * 128 + k8 * 16) ^ ((row & 7) << 4))) = v;
        }
        __syncthreads();

        #pragma unroll
        for (int kb = 0; kb < 2; ++kb) {
            short8 af[M_REP], bfr[N_REP];
            #pragma unroll
            for (int m = 0; m < M_REP; ++m) {
                int row = wm * WROWS + m * 16 + l15;
                af[m] = *(const short8*)((const char*)sA +
                        ((row * 128 + kb * 64 + lhi * 16) ^ ((row & 7) << 4)));
            }
            #pragma unroll
            for (int n = 0; n < N_REP; ++n) {
                int colr = wn0 + n * 16 + l15;
                bfr[n] = *(const short8*)((const char*)sW +
                         ((colr * 128 + kb * 64 + lhi * 16) ^ ((colr & 7) << 4)));
            }
            #pragma unroll
            for (int m = 0; m < M_REP; ++m)
                #pragma unroll
                for (int n = 0; n < N_REP; ++n)
                    acc[m][n] = __builtin_amdgcn_mfma_f32_16x16x32_bf16(af[m], bfr[n], acc[m][n], 0, 0, 0);
        }
    }

    float bv[N_REP];
    #pragma unroll
    for (int n = 0; n < N_REP; ++n) bv[n] = bias ? bias[wn0 + n * 16 + l15] : 0.f;

    #pragma unroll
    for (int m = 0; m < M_REP; ++m) {
        #pragma unroll
        for (int r = 0; r < 4; ++r) {
            int grow = r0 + wm * WROWS + m * 16 + lhi * 4 + r;
            if (grow < N) {
                #pragma unroll
                for (int n = 0; n < N_REP; ++n) {
                    int colr = wn0 + n * 16 + l15;
                    float v = acc[m][n][r] + bv[n];
                    if (HAS_ADD) v += bf2f(add[(size_t)grow * OD + colr]);
                    if (RELU) v = fmaxf(v, 0.f);
                    if (OUT_F32) ((float*)outp)[(size_t)grow * OD + colr] = v;
                    else ((ushort*)outp)[(size_t)grow * OD + colr] = f2bf(v);
                }
            }
        }
    }
}

extern "C" void kernel_launch(void* const* d_in, const int* in_sizes, int n_in,
                              void* d_out, int out_size, void* d_ws, size_t ws_size,
                              hipStream_t stream) {
    const float* x     = (const float*)d_in[0];
    const int*   eidx  = (const int*)d_in[1];
    const float* emb_W = (const float*)d_in[2];
    const float* emb_b = (const float*)d_in[3];
    const float* Wl0   = (const float*)d_in[4];
    const float* bl0   = (const float*)d_in[5];
    const float* Wr0   = (const float*)d_in[6];
    const float* Wl1   = (const float*)d_in[7];
    const float* bl1   = (const float*)d_in[8];
    const float* Wr1   = (const float*)d_in[9];
    const float* Wl2   = (const float*)d_in[10];
    const float* bl2   = (const float*)d_in[11];
    const float* Wr2   = (const float*)d_in[12];

    const int N = in_sizes[0] / NODE_D;
    const int E = in_sizes[1] / 2;
    const int* src = eidx;
    const int* dst = eidx + E;

    // ---- workspace layout (bf16 arrays first for 16B alignment) ----
    char* w = (char*)d_ws;
    ushort* x_bf    = (ushort*)w; w += (size_t)N * 128 * sizeof(ushort);
    ushort* h_bf    = (ushort*)w; w += (size_t)N * 128 * sizeof(ushort);
    ushort* mean_bf = (ushort*)w; w += (size_t)N * 128 * sizeof(ushort);
    ushort* wbf     = (ushort*)w; w += (size_t)98304 * sizeof(ushort);
    int* deg    = (int*)w; w += (size_t)N * sizeof(int);
    int* rowptr = (int*)w; w += (size_t)(N + 1) * sizeof(int);
    int* cursor = (int*)w; w += (size_t)N * sizeof(int);
    int* bsums  = (int*)w; w += (size_t)256 * sizeof(int);
    int* col    = (int*)w; w += (size_t)E * sizeof(int);

    const ushort* embB = wbf;
    const ushort* Wl0B = wbf + 16384;
    const ushort* Wr0B = wbf + 32768;
    const ushort* Wl1B = wbf + 49152;
    const ushort* Wr1B = wbf + 65536;
    const ushort* Wl2B = wbf + 81920;
    const ushort* Wr2B = wbf + 90112;

    // layer-2 64-dim buffers alias mean_bf
    ushort* g2 = mean_bf;
    ushort* ga = mean_bf + (size_t)N * 64;

    const int TPB = 256;

    // ---- conversions ----
    hipLaunchKernelGGL(k_cvt, dim3(2048), dim3(TPB), 0, stream, x, x_bf, N * 128 / 4);
    hipLaunchKernelGGL(k_cvt_w, dim3(384), dim3(TPB), 0, stream,
                       emb_W, Wl0, Wr0, Wl1, Wr1, Wl2, Wr2, wbf);

    // ---- CSR build ----
    hipMemsetAsync(deg, 0, (size_t)N * sizeof(int), stream);
    hipLaunchKernelGGL(k_hist, dim3((E + TPB - 1) / TPB), dim3(TPB), 0, stream, dst, deg, E);
    const int NB = (N + SCAN_T * SCAN_I - 1) / (SCAN_T * SCAN_I);
    hipLaunchKernelGGL(k_scan_bsum, dim3(NB), dim3(SCAN_T), 0, stream, deg, bsums, N);
    hipLaunchKernelGGL(k_scan_bsum_excl, dim3(1), dim3(1), 0, stream, bsums, NB, rowptr + N);
    hipLaunchKernelGGL(k_scan_final, dim3(NB), dim3(SCAN_T), 0, stream, deg, bsums, rowptr, cursor, N);
    hipLaunchKernelGGL(k_fill, dim3((E + TPB - 1) / TPB), dim3(TPB), 0, stream, src, dst, cursor, col, E);

    const int dgrid = (N + 127) / 128;
    const int agrid = (N + 3) / 4;

    // ---- embedding: h = x @ emb_W.T + emb_b ----
    hipLaunchKernelGGL((k_mm<128, false, false, false, false>), dim3(dgrid), dim3(TPB), 0, stream,
                       x_bf, (const ushort*)nullptr, embB, (const ushort*)nullptr,
                       emb_b, (const ushort*)nullptr, h_bf, N);

    // ---- layer 0: h = relu(mean@Wl0.T + bl0 + h@Wr0.T) ----
    hipLaunchKernelGGL((k_aggb<128>), dim3(agrid), dim3(TPB), 0, stream, h_bf, rowptr, col, mean_bf, N);
    hipLaunchKernelGGL((k_mm<128, true, false, true, false>), dim3(dgrid), dim3(TPB), 0, stream,
                       mean_bf, h_bf, Wl0B, Wr0B, bl0, (const ushort*)nullptr, h_bf, N);

    // ---- layer 1 ----
    hipLaunchKernelGGL((k_aggb<128>), dim3(agrid), dim3(TPB), 0, stream, h_bf, rowptr, col, mean_bf, N);
    hipLaunchKernelGGL((k_mm<128, true, false, true, false>), dim3(dgrid), dim3(TPB), 0, stream,
                       mean_bf, h_bf, Wl1B, Wr1B, bl1, (const ushort*)nullptr, h_bf, N);

    // ---- layer 2: pre-transform (linearity), aggregate 64-dim, root + add ----
    hipLaunchKernelGGL((k_mm<64, false, false, false, false>), dim3(dgrid), dim3(TPB), 0, stream,
                       h_bf, (const ushort*)nullptr, Wl2B, (const ushort*)nullptr,
                       (const float*)nullptr, (const ushort*)nullptr, g2, N);
    hipLaunchKernelGGL((k_aggb<64>), dim3(agrid), dim3(TPB), 0, stream, g2, rowptr, col, ga, N);
    hipLaunchKernelGGL((k_mm<64, false, true, false, true>), dim3(dgrid), dim3(TPB), 0, stream,
                       h_bf, (const ushort*)nullptr, Wr2B, (const ushort*)nullptr,
                       bl2, ga, d_out, N);
}